// Round 8
// baseline (325.358 us; speedup 1.0000x reference)
//
#include <hip/hip_runtime.h>
#include <hip/hip_bf16.h>

#define NPOS   100
#define BATCH  1024
#define DIN    384
#define DOUT   384
#define XROW   (NPOS * DIN)      // 38400 floats, batch-dim stride of x and out
#define WSLICE (DIN * DOUT)

#define BM 128
#define BN 128
#define BK 32
#define NK (DIN / BK)            // 12 K-steps
#define PA 40                    // pitch (shorts): 80B rows
#define PB 40

typedef __attribute__((ext_vector_type(8))) short bf16x8;
typedef __attribute__((ext_vector_type(16))) float f32x16;

__device__ __forceinline__ unsigned f2bfu(float f) {
  return (unsigned)__builtin_bit_cast(unsigned short, __float2bfloat16(f));
}
__device__ __forceinline__ unsigned pack2(float a, float b) {
  return f2bfu(a) | (f2bfu(b) << 16);
}
__device__ __forceinline__ unsigned ext16(unsigned u, int h) {
  return h ? (u >> 16) : (u & 0xffffu);
}
__device__ __forceinline__ void barrier_nodrain() {
  asm volatile("s_waitcnt lgkmcnt(0)" ::: "memory");
  __builtin_amdgcn_s_barrier();
}

// ---------------------------------------------------------------------------
// 1) probe_stream: ideal-pattern traffic probe. Reads x (157MB) + w (59MB)
//    fully coalesced, writes full out (157MB). Measures deliverable BW for
//    the op's ideal byte count. Output garbage — champion overwrites later.
// ---------------------------------------------------------------------------
__global__ __launch_bounds__(256) void probe_stream(
    const float4* __restrict__ x4, const float4* __restrict__ w4,
    float4* __restrict__ out4)
{
  const int XN4 = 9830400;   // 1024*38400/4
  const int WN4 = 3686400;   // 100*147456/4
  const int ON4 = 9830400;
  const int tid = blockIdx.x * blockDim.x + threadIdx.x;
  const int stride = gridDim.x * blockDim.x;
  float4 s = float4{0.f, 0.f, 0.f, 0.f};
  for (int i = tid; i < XN4; i += stride) {
    float4 v = x4[i];
    s.x += v.x; s.y += v.y; s.z += v.z; s.w += v.w;
  }
  for (int i = tid; i < WN4; i += stride) {
    float4 v = w4[i];
    s.x += v.x; s.y += v.y; s.z += v.z; s.w += v.w;
  }
  for (int i = tid; i < ON4; i += stride) out4[i] = s;
}

// ---------------------------------------------------------------------------
// 2) gemm_nobar: ZERO barriers. Each wave owns an independent 64x64 output
//    tile with wave-private single-buffered LDS (per-wave DS ops are
//    in-order: frag reads of step k issued before staging writes of k+1,
//    so no hazard, no syncthreads anywhere). Output may be overwritten.
// ---------------------------------------------------------------------------
__global__ __launch_bounds__(256) void gemm_nobar(
    const float* __restrict__ x, const float* __restrict__ w,
    const float* __restrict__ bias, float* __restrict__ out)
{
  __shared__ short sA[4][64 * PA];   // per-wave A: 64 rows x 32 k
  __shared__ short sB[4][64 * PB];   // per-wave B^T: 64 o x 32 k

  const int tid  = threadIdx.x;
  const int lane = tid & 63;
  const int wave = tid >> 6;
  const int l31  = lane & 31;
  const int kHi  = (lane >> 5) * 8;

  // slice-grouped swizzle (same as champion): 2400 = 8*300
  const int bid   = blockIdx.x;
  const int swz   = (bid & 7) * 300 + (bid >> 3);
  const int slice = swz / 24;
  const int r     = swz - slice * 24;
  const int tile  = r * 4 + wave;        // 0..95 per slice
  const int rt    = tile / 6;            // 16 row-tiles (64 rows)
  const int ct    = tile - rt * 6;       // 6 col-tiles (64 cols)

  const float* xbase = x    + (size_t)rt * 64 * XROW + (size_t)slice * DIN;
  const float* wbase = w    + (size_t)slice * WSLICE + ct * 64;
  const float* bbase = bias + (size_t)slice * DOUT   + ct * 64;
  float*       obase = out  + (size_t)rt * 64 * XROW + (size_t)slice * DOUT + ct * 64;

  // A staging map: inst i -> rows (lane>>3)+8i, 16B chunk (lane&7)
  const int a_c = lane & 7;
  const int a_r = lane >> 3;
  // B staging map: inst j -> k-row 8*(lane>>4)+j, o-chunk lane&15 (256B runs)
  const int b_oc = lane & 15;
  const int b_h  = lane >> 4;

  unsigned au[8][2];
  unsigned bu[8][2];

  auto G2R = [&](int k0) {
#pragma unroll
    for (int i = 0; i < 8; ++i) {
      const float4 v = *reinterpret_cast<const float4*>(
          xbase + (size_t)(a_r + 8 * i) * XROW + k0 + a_c * 4);
      au[i][0] = pack2(v.x, v.y);
      au[i][1] = pack2(v.z, v.w);
    }
#pragma unroll
    for (int j = 0; j < 8; ++j) {
      const float4 v = *reinterpret_cast<const float4*>(
          wbase + (size_t)(k0 + 8 * b_h + j) * DOUT + b_oc * 4);
      bu[j][0] = pack2(v.x, v.y);
      bu[j][1] = pack2(v.z, v.w);
    }
  };

  auto R2L = [&]() {
#pragma unroll
    for (int i = 0; i < 8; ++i)
      *reinterpret_cast<uint2*>(&sA[wave][(a_r + 8 * i) * PA + a_c * 4]) =
          uint2{au[i][0], au[i][1]};
    // B^T transpose: row o = b_oc*4+c gets 8 contiguous k at 8*b_h (b128)
#pragma unroll
    for (int c = 0; c < 4; ++c) {
      uint4 t;
      t.x = ext16(bu[0][c >> 1], c & 1) | (ext16(bu[1][c >> 1], c & 1) << 16);
      t.y = ext16(bu[2][c >> 1], c & 1) | (ext16(bu[3][c >> 1], c & 1) << 16);
      t.z = ext16(bu[4][c >> 1], c & 1) | (ext16(bu[5][c >> 1], c & 1) << 16);
      t.w = ext16(bu[6][c >> 1], c & 1) | (ext16(bu[7][c >> 1], c & 1) << 16);
      *reinterpret_cast<uint4*>(&sB[wave][(b_oc * 4 + c) * PB + 8 * b_h]) = t;
    }
  };

  f32x16 acc[2][2];
#pragma unroll
  for (int m = 0; m < 2; ++m)
#pragma unroll
    for (int n = 0; n < 2; ++n)
#pragma unroll
      for (int q = 0; q < 16; ++q)
        acc[m][n][q] = 0.f;

  G2R(0);
  R2L();
  G2R(BK);

#pragma unroll
  for (int ks = 0; ks < NK; ++ks) {
    bf16x8 af[2][2], bf[2][2];
#pragma unroll
    for (int kk = 0; kk < 2; ++kk)
#pragma unroll
      for (int m = 0; m < 2; ++m)
        af[kk][m] = *reinterpret_cast<const bf16x8*>(
            &sA[wave][(m * 32 + l31) * PA + kk * 16 + kHi]);
#pragma unroll
    for (int kk = 0; kk < 2; ++kk)
#pragma unroll
      for (int n = 0; n < 2; ++n)
        bf[kk][n] = *reinterpret_cast<const bf16x8*>(
            &sB[wave][(n * 32 + l31) * PB + kk * 16 + kHi]);
    if (ks + 1 < NK) R2L();               // in-order DS: no hazard with reads
    if (ks + 2 < NK) G2R((ks + 2) * BK);
#pragma unroll
    for (int kk = 0; kk < 2; ++kk)
#pragma unroll
      for (int m = 0; m < 2; ++m)
#pragma unroll
        for (int n = 0; n < 2; ++n)
          acc[m][n] = __builtin_amdgcn_mfma_f32_32x32x16_bf16(
              af[kk][m], bf[kk][n], acc[m][n], 0, 0, 0);
  }

  float bv[2];
#pragma unroll
  for (int n = 0; n < 2; ++n) bv[n] = bbase[n * 32 + l31];
  const int rbase = (lane >> 5) << 2;
#pragma unroll
  for (int m = 0; m < 2; ++m)
#pragma unroll
    for (int n = 0; n < 2; ++n) {
      const int c = n * 32 + l31;
#pragma unroll
      for (int q = 0; q < 16; ++q) {
        const int row = rbase + m * 32 + (q & 3) + 8 * (q >> 2);
        obase[(size_t)row * XROW + c] = acc[m][n][q] + bv[n];
      }
    }
}

// ---------------------------------------------------------------------------
// 3) gemm_champion: exact R6 kernel (best validated: 143us rocprof).
//    Runs LAST so d_out is correct.
// ---------------------------------------------------------------------------
__global__ __launch_bounds__(256, 4) void gemm_champion(
    const float* __restrict__ x, const float* __restrict__ w,
    const float* __restrict__ bias, float* __restrict__ out)
{
  __shared__ short lA[2][BM * PA];
  __shared__ short lB[2][BN * PB];

  const int tid  = threadIdx.x;
  const int lane = tid & 63;
  const int wave = tid >> 6;
  const int wm   = wave >> 1;
  const int wn   = wave & 1;
  const int l31  = lane & 31;
  const int kHi  = (lane >> 5) * 8;
  const int gHalf = lane >> 5;
  const int xr   = (l31 >> 3) & 3;

  const int bid   = blockIdx.x;
  const int swz   = (bid & 7) * 300 + (bid >> 3);
  const int slice = swz / 24;
  const int rem   = swz - slice * 24;
  const int mt    = rem / 3;
  const int nt    = rem - mt * 3;

  const float* xbase = x    + (size_t)mt * BM * XROW + (size_t)slice * DIN;
  const float* wbase = w    + (size_t)slice * WSLICE + nt * BN;
  const float* bbase = bias + (size_t)slice * DOUT   + nt * BN;
  float*       obase = out  + (size_t)mt * BM * XROW + (size_t)slice * DOUT + nt * BN;

  const int a_c4   = tid & 7;
  const int a_row0 = tid >> 3;
  const int b_kb   = tid & 7;
  const int b_oq   = tid >> 3;
  const int b_gw   = (b_kb >> 1) ^ ((b_oq >> 1) & 3);
  const int b_h    = b_kb & 1;

  unsigned au[4][2];
  unsigned bu[4][2];

  auto G2R = [&](int k0) {
#pragma unroll
    for (int i = 0; i < 4; ++i) {
      const float4 v = *reinterpret_cast<const float4*>(
          xbase + (size_t)(a_row0 + 32 * i) * XROW + k0 + a_c4 * 4);
      au[i][0] = pack2(v.x, v.y);
      au[i][1] = pack2(v.z, v.w);
    }
#pragma unroll
    for (int dk = 0; dk < 4; ++dk) {
      const float4 v = *reinterpret_cast<const float4*>(
          wbase + (size_t)(k0 + b_kb * 4 + dk) * DOUT + b_oq * 4);
      bu[dk][0] = pack2(v.x, v.y);
      bu[dk][1] = pack2(v.z, v.w);
    }
  };

  auto R2L = [&](int buf) {
#pragma unroll
    for (int i = 0; i < 4; ++i)
      *reinterpret_cast<uint2*>(&lA[buf][(a_row0 + 32 * i) * PA + a_c4 * 4]) =
          uint2{au[i][0], au[i][1]};
#pragma unroll
    for (int c = 0; c < 4; ++c) {
      uint2 t;
      t.x = ext16(bu[0][c >> 1], c & 1) | (ext16(bu[1][c >> 1], c & 1) << 16);
      t.y = ext16(bu[2][c >> 1], c & 1) | (ext16(bu[3][c >> 1], c & 1) << 16);
      *reinterpret_cast<uint2*>(
          &lB[buf][(b_oq * 4 + c) * PB + b_gw * 8 + b_h * 4]) = t;
    }
  };

  f32x16 acc[2][2];
#pragma unroll
  for (int m = 0; m < 2; ++m)
#pragma unroll
    for (int n = 0; n < 2; ++n)
#pragma unroll
      for (int q = 0; q < 16; ++q)
        acc[m][n][q] = 0.f;

  G2R(0);
  R2L(0);
  barrier_nodrain();
  G2R(BK);

  auto STEP = [&](int ks, int cb) {
    if (ks + 1 < NK) R2L(cb ^ 1);
    if (ks + 2 < NK) G2R((ks + 2) * BK);
    bf16x8 af[2][2], bf[2][2];
#pragma unroll
    for (int kk = 0; kk < 2; ++kk)
#pragma unroll
      for (int m = 0; m < 2; ++m)
        af[kk][m] = *reinterpret_cast<const bf16x8*>(
            &lA[cb][(wm * 64 + m * 32 + l31) * PA + kk * 16 + kHi]);
#pragma unroll
    for (int kk = 0; kk < 2; ++kk)
#pragma unroll
      for (int n = 0; n < 2; ++n) {
        const int g = (kk * 2 + gHalf) ^ xr;
        bf[kk][n] = *reinterpret_cast<const bf16x8*>(
            &lB[cb][(wn * 64 + n * 32 + l31) * PB + g * 8]);
      }
#pragma unroll
    for (int kk = 0; kk < 2; ++kk)
#pragma unroll
      for (int m = 0; m < 2; ++m)
#pragma unroll
        for (int n = 0; n < 2; ++n)
          acc[m][n] = __builtin_amdgcn_mfma_f32_32x32x16_bf16(
              af[kk][m], bf[kk][n], acc[m][n], 0, 0, 0);
    barrier_nodrain();
  };

#pragma unroll
  for (int ks = 0; ks < NK; ks += 2) {
    STEP(ks, 0);
    STEP(ks + 1, 1);
  }

  float bv[2];
#pragma unroll
  for (int n = 0; n < 2; ++n) bv[n] = bbase[wn * 64 + n * 32 + l31];

  const int rbase = wm * 64 + ((lane >> 5) << 2);
#pragma unroll
  for (int m = 0; m < 2; ++m)
#pragma unroll
    for (int n = 0; n < 2; ++n) {
      const int c = wn * 64 + n * 32 + l31;
#pragma unroll
      for (int q = 0; q < 16; ++q) {
        const int row = rbase + m * 32 + (q & 3) + 8 * (q >> 2);
        obase[(size_t)row * XROW + c] = acc[m][n][q] + bv[n];
      }
    }
}

extern "C" void kernel_launch(void* const* d_in, const int* in_sizes, int n_in,
                              void* d_out, int out_size, void* d_ws, size_t ws_size,
                              hipStream_t stream) {
  const float* x  = (const float*)d_in[0];
  const float* w  = (const float*)d_in[1];
  const float* b  = (const float*)d_in[2];
  float* out      = (float*)d_out;
  const int grid  = NPOS * (BATCH / BM) * (DOUT / BN);  // 2400

  // 1) ideal-pattern BW probe (garbage into out)
  probe_stream<<<2048, 256, 0, stream>>>(
      (const float4*)x, (const float4*)w, (float4*)out);
  // 2) zero-barrier structural variant (output ignored)
  gemm_nobar<<<grid, 256, 0, stream>>>(x, w, b, out);
  // 3) validated champion last -> d_out correct
  gemm_champion<<<grid, 256, 0, stream>>>(x, w, b, out);
}